// Round 3
// baseline (26685.825 us; speedup 1.0000x reference)
//
#include <hip/hip_runtime.h>
#include <hip/hip_bf16.h>
#include <stdint.h>

// NeuralFSDE: 1000 sequential steps of x += mlp_d(x)*dt + mlp_s(x)*(fgn*dt^H)
// B=128, S=256, Hd=512.
// Round 3: ALL-REGISTER-WEIGHTS, ZERO-COMMUNICATION design.
//   Rounds 0-2 proved the per-step cross-wg exchange is ~4 serialized
//   ~900cy memory-latency legs and scope tuning can't shrink it (sc1 ==
//   sc0sc1 completion point; WRITE_SIZE unchanged). So eliminate it:
//   8 wgs x 1024 threads; each wg holds the FULL four weight matrices as
//   bf16 MFMA fragments in registers (1 KB/thread = 256 VGPRs; cap 512 at
//   4 waves/SIMD) and owns 16 batch rows for all 1000 steps. Per step:
//   GEMM1 (operand-swapped so hidden lands lane-contiguous -> ds_write_b64),
//   tanh, GEMM2, x-update -- all in-CU with 2 __syncthreads. No flags, no
//   partials, no workspace. fp32 master state lives in registers.

typedef __attribute__((ext_vector_type(8))) short bf16x8;
typedef __attribute__((ext_vector_type(4))) float f32x4;
typedef __attribute__((ext_vector_type(4))) unsigned short u16x4;

#define MFMA16(a, b, c) __builtin_amdgcn_mfma_f32_16x16x32_bf16((a), (b), (c), 0, 0, 0)

__device__ __forceinline__ unsigned short f2bf(float f) {
  union { float f; uint32_t u; } v; v.f = f;
  return (unsigned short)((v.u + 0x7fffu + ((v.u >> 16) & 1u)) >> 16);
}

__device__ __forceinline__ float fast_tanh(float z) {
  float az = __builtin_fabsf(z);
  float e = __expf(-2.0f * az);
  float r = (1.0f - e) * __builtin_amdgcn_rcpf(1.0f + e);
  return z < 0.0f ? -r : r;
}

__global__ __launch_bounds__(1024, 1) void fsde_kernel(
    const float* __restrict__ x0,
    const float* __restrict__ Wd1, const float* __restrict__ bd1,
    const float* __restrict__ Wd2, const float* __restrict__ bd2,
    const float* __restrict__ Ws1, const float* __restrict__ bs1,
    const float* __restrict__ Ws2, const float* __restrict__ bs2,
    const float* __restrict__ rawh,
    const float* __restrict__ fgn,
    const int* __restrict__ nsp,
    float* __restrict__ out)
{
  // LDS. Row strides chosen so stride % 32 dwords == 4 (proven 2-way-alias
  // pattern from the previous kernel: 264 shorts = 132 dw, 520 shorts = 260 dw).
  __shared__ __align__(16) unsigned short Xs[16 * 264];    // x tile bf16   (8.4 KB)
  __shared__ __align__(16) unsigned short HdT[16 * 520];   // drift hidden  (16.6 KB)
  __shared__ __align__(16) unsigned short HsT[16 * 520];   // diff hidden   (16.6 KB)

  const int tid = threadIdx.x;
  const int lane = tid & 63;
  const int wv = tid >> 6;   // wave 0..15
  const int q = lane >> 4;   // quad 0..3
  const int cl = lane & 15;

  const int bid = blockIdx.x;   // 0..7
  const int r0 = bid * 16;      // this wg's batch rows [r0, r0+16)

  const int NS = nsp[0];
  const float dt = 1.0f / (float)NS;  // T_MAX = 1.0
  const float Hh = 0.98f / (1.0f + expf(-rawh[0])) + 0.01f;
  const float nsc = expf(Hh * logf(dt));  // dt^H

  // ---- stage ALL weight fragments into registers (direct global loads) ----
  // GEMM1 is computed swapped: C1 = W1^T * X^T  (M=hidden, N=batch-row).
  // A-frag (W1^T): lane(q,cl) holds W1[k=kt*32+q*8+e][hcol], hcol=wv*32+i*16+cl
  //   -> identical data layout to the old B-frag; element [k][h] = W1[k*512+h].
  // GEMM2 standard: B-frag (W2): lane holds W2[k=kt*32+q*8+e][col], col=wv*16+cl.
  bf16x8 w1d[2][8], w1s[2][8], w2d[16], w2s[16];
#pragma unroll
  for (int i = 0; i < 2; ++i) {
    const int hcol = wv * 32 + i * 16 + cl;
#pragma unroll
    for (int kt = 0; kt < 8; ++kt) {
      const int kb = kt * 32 + q * 8;
      bf16x8 fd, fs;
#pragma unroll
      for (int e = 0; e < 8; ++e) {
        fd[e] = (short)f2bf(Wd1[(size_t)(kb + e) * 512 + hcol]);
        fs[e] = (short)f2bf(Ws1[(size_t)(kb + e) * 512 + hcol]);
      }
      w1d[i][kt] = fd;
      w1s[i][kt] = fs;
    }
  }
  const int colg2 = wv * 16 + cl;  // this lane's owned state column
#pragma unroll
  for (int kt = 0; kt < 16; ++kt) {
    const int kb = kt * 32 + q * 8;
    bf16x8 fd, fs;
#pragma unroll
    for (int e = 0; e < 8; ++e) {
      fd[e] = (short)f2bf(Wd2[(size_t)(kb + e) * 256 + colg2]);
      fs[e] = (short)f2bf(Ws2[(size_t)(kb + e) * 256 + colg2]);
    }
    w2d[kt] = fd;
    w2s[kt] = fs;
  }

  // biases: layer-1 per lane as contiguous f32x4 at hidden = wv*32+i*16+q*4+r
  f32x4 b1d_[2], b1s_[2];
#pragma unroll
  for (int i = 0; i < 2; ++i) {
    b1d_[i] = *(const f32x4*)(bd1 + wv * 32 + i * 16 + q * 4);
    b1s_[i] = *(const f32x4*)(bs1 + wv * 32 + i * 16 + q * 4);
  }
  const float b2d_ = bd2[colg2];
  const float b2s_ = bs2[colg2];

  // ---- persistent fp32 state: lane(q,cl) of wave wv owns
  //      rows r0+q*4+r (r=0..3), column colg2 ----
  f32x4 xr;
#pragma unroll
  for (int r = 0; r < 4; ++r)
    xr[r] = x0[(size_t)(r0 + q * 4 + r) * 256 + colg2];

  // seed Xs (bf16) and trajectory slot 0; (wv cols x q,r rows) tile exactly
  // covers the 16x256 tile with no duplication.
#pragma unroll
  for (int r = 0; r < 4; ++r) {
    Xs[(q * 4 + r) * 264 + colg2] = f2bf(xr[r]);
    out[(size_t)(r0 + q * 4 + r) * (size_t)(NS + 1) * 256 + colg2] = xr[r];
  }
  __syncthreads();

  for (int t = 0; t < NS; ++t) {
    // noise prefetch (consumed ~2000cy later, after both GEMMs)
    f32x4 nf;
#pragma unroll
    for (int r = 0; r < 4; ++r)
      nf[r] = fgn[((size_t)t * 128 + (size_t)(r0 + q * 4 + r)) * 256 + colg2];

    // ---- GEMM1 (swapped): H^T[hidden, row] = W1^T x X^T ----
    // B-operand = x rows: lane(q,cl) holds x[row=cl][k=kt*32+q*8..+7]
    f32x4 hd0 = {0.f,0.f,0.f,0.f}, hd1 = {0.f,0.f,0.f,0.f};
    f32x4 hs0 = {0.f,0.f,0.f,0.f}, hs1 = {0.f,0.f,0.f,0.f};
#pragma unroll
    for (int kt = 0; kt < 8; ++kt) {
      bf16x8 xa = *(const bf16x8*)&Xs[cl * 264 + kt * 32 + q * 8];
      hd0 = MFMA16(w1d[0][kt], xa, hd0);
      hd1 = MFMA16(w1d[1][kt], xa, hd1);
      hs0 = MFMA16(w1s[0][kt], xa, hs0);
      hs1 = MFMA16(w1s[1][kt], xa, hs1);
    }
    // C1-frag: lane holds batch row = cl, hidden = wv*32+i*16+q*4+r (r consec)
    // -> bias + tanh + pack 4 -> one ds_write_b64 per (i, mlp) into [row][hid]
#pragma unroll
    for (int i = 0; i < 2; ++i) {
      f32x4 vd = (i ? hd1 : hd0);
      f32x4 vs = (i ? hs1 : hs0);
      u16x4 hud, hus;
#pragma unroll
      for (int r = 0; r < 4; ++r) {
        hud[r] = f2bf(fast_tanh(vd[r] + b1d_[i][r]));
        hus[r] = f2bf(fast_tanh(vs[r] + b1s_[i][r]));
      }
      *(u16x4*)&HdT[cl * 520 + wv * 32 + i * 16 + q * 4] = hud;
      *(u16x4*)&HsT[cl * 520 + wv * 32 + i * 16 + q * 4] = hus;
    }
    __syncthreads();

    // ---- GEMM2 (standard): y[row, col] = H x W2, full K=512 in-wave ----
    f32x4 pd = {0.f,0.f,0.f,0.f}, ps = {0.f,0.f,0.f,0.f};
#pragma unroll
    for (int kt = 0; kt < 16; ++kt) {
      bf16x8 ad = *(const bf16x8*)&HdT[cl * 520 + kt * 32 + q * 8];
      pd = MFMA16(ad, w2d[kt], pd);
      bf16x8 as2 = *(const bf16x8*)&HsT[cl * 520 + kt * 32 + q * 8];
      ps = MFMA16(as2, w2s[kt], ps);
    }

    // ---- x update (C2-frag layout == persistent state layout) ----
#pragma unroll
    for (int r = 0; r < 4; ++r)
      xr[r] += (pd[r] + b2d_) * dt + (ps[r] + b2s_) * (nf[r] * nsc);

#pragma unroll
    for (int r = 0; r < 4; ++r) {
      Xs[(q * 4 + r) * 264 + colg2] = f2bf(xr[r]);
      out[(size_t)(r0 + q * 4 + r) * (size_t)(NS + 1) * 256 +
          (size_t)(t + 1) * 256 + colg2] = xr[r];
    }
    __syncthreads();
  }
}

extern "C" void kernel_launch(void* const* d_in, const int* in_sizes, int n_in,
                              void* d_out, int out_size, void* d_ws, size_t ws_size,
                              hipStream_t stream) {
  const float* x0  = (const float*)d_in[0];
  const float* Wd1 = (const float*)d_in[1];
  const float* bd1 = (const float*)d_in[2];
  const float* Wd2 = (const float*)d_in[3];
  const float* bd2 = (const float*)d_in[4];
  const float* Ws1 = (const float*)d_in[5];
  const float* bs1 = (const float*)d_in[6];
  const float* Ws2 = (const float*)d_in[7];
  const float* bs2 = (const float*)d_in[8];
  const float* rawh = (const float*)d_in[9];
  const float* fgn = (const float*)d_in[10];
  const int* nsp = (const int*)d_in[11];
  float* out = (float*)d_out;

  fsde_kernel<<<dim3(8), dim3(1024), 0, stream>>>(
      x0, Wd1, bd1, Wd2, bd2, Ws1, bs1, Ws2, bs2, rawh, fgn, nsp, out);
}

// Round 5
// 4307.998 us; speedup vs baseline: 6.1945x; 6.1945x over previous
//
#include <hip/hip_runtime.h>
#include <hip/hip_bf16.h>
#include <stdint.h>

// NeuralFSDE: 1000 sequential steps of x += mlp_d(x)*dt + mlp_s(x)*(fgn*dt^H)
// B=128, S=256, Hd=512. Weight-stationary sharded design (proven 3000us):
//   32 clusters x 8 wgs; cluster owns 4 batch rows; wg j holds a 128-wide
//   hidden slice of (drift|diff) MLP in registers; partials exchanged per step.
// Round 5: TAGGED-PAIR EXCHANGE, flat-address gather.
//   Each partial is an 8B (fp32 value, u32 tag=t+1) pair stored by ONE
//   global_store_dwordx2 (naturally aligned -> single transaction, no tear).
//   Consumer issues gather loads IMMEDIATELY after its own stores (no drain:
//   store & load latency overlap) and retries until every tag == t+1; the
//   tag validates its own 8 bytes. No flags, no poll, no memset (workspace
//   0xAA poison != any valid tag). Liveness: tags are written uncondition-
//   ally; double-buffer backpressure unchanged -> hang-impossible.
//   Round-4 compile fix: gather uses flat 64-bit VGPR addresses ("v"), not
//   the saddr form whose "s" operands the allocator demoted to VGPRs.
//   Arithmetic bit-identical to the 3000us baseline.

typedef __attribute__((ext_vector_type(8))) short bf16x8;
typedef __attribute__((ext_vector_type(4))) float f32x4;
typedef __attribute__((ext_vector_type(4))) unsigned short u16x4;
typedef __attribute__((ext_vector_type(2))) unsigned int u32x2;
typedef __attribute__((ext_vector_type(4))) unsigned int u32x4;

#define MFMA16(a, b, c) __builtin_amdgcn_mfma_f32_16x16x32_bf16((a), (b), (c), 0, 0, 0)

__device__ __forceinline__ unsigned short f2bf(float f) {
  union { float f; uint32_t u; } v; v.f = f;
  return (unsigned short)((v.u + 0x7fffu + ((v.u >> 16) & 1u)) >> 16);
}

__device__ __forceinline__ float fast_tanh(float z) {
  float az = __builtin_fabsf(z);
  float e = __expf(-2.0f * az);
  float r = (1.0f - e) * __builtin_amdgcn_rcpf(1.0f + e);
  return z < 0.0f ? -r : r;
}

__global__ __launch_bounds__(256, 1) void fsde_kernel(
    const float* __restrict__ x0,
    const float* __restrict__ Wd1, const float* __restrict__ bd1,
    const float* __restrict__ Wd2, const float* __restrict__ bd2,
    const float* __restrict__ Ws1, const float* __restrict__ bs1,
    const float* __restrict__ Ws2, const float* __restrict__ bs2,
    const float* __restrict__ rawh,
    const float* __restrict__ fgn,
    const int* __restrict__ nsp,
    float* __restrict__ out,
    float* __restrict__ part)   // [2][32][8][1024] (fp32,u32-tag) pairs = 4 MB
{
  // LDS: strides padded so stride % 32 dwords == 4 -> MFMA frag reads are
  // 2-way bank aliased (free, m136); rows 16B aligned for ds_read_b128.
  __shared__ __align__(16) unsigned short Xs[16 * 264];   // x tile, bf16
  __shared__ __align__(16) unsigned short Hs[16 * 136];   // hidden tile, bf16
  __shared__ __align__(16) unsigned short STG[8704];      // weight staging scratch
  __shared__ float B1[128];

  const int tid = threadIdx.x;
  const int lane = tid & 63;
  const int wv = tid >> 6;   // wave 0..3
  const int q = lane >> 4;   // quad 0..3
  const int cl = lane & 15;

  // block -> (cluster c, shard j); cluster's 8 blocks share bid%8 (same XCD
  // under round-robin dispatch -- perf heuristic only; correctness is
  // system-scope + tag-validated).
  const int bid = blockIdx.x;
  const int c = (bid & 7) * 4 + ((bid >> 3) >> 3);  // 0..31
  const int j = (bid >> 3) & 7;                     // 0..7

  const int NS = nsp[0];
  const float dt = 1.0f / (float)NS;  // T_MAX = 1.0
  const float Hh = 0.98f / (1.0f + expf(-rawh[0])) + 0.01f;
  const float nsc = expf(Hh * logf(dt));  // dt^H

  const float* W1g = (j < 4) ? Wd1 : Ws1;  // [256][512]
  const float* W2g = (j < 4) ? Wd2 : Ws2;  // [512][256]
  const float* b1g = (j < 4) ? bd1 : bs1;
  const int jj = (j & 3) * 128;  // hidden slice start

  // ---- stage layer-1 weight frags into registers (per-wave 32-col chunks) ----
  bf16x8 w1f[2][8];
  for (int wc = 0; wc < 4; ++wc) {
    __syncthreads();
    for (int idx = tid; idx < 32 * 256; idx += 256) {
      int n = idx & 31, k = idx >> 5;
      STG[n * 264 + k] = f2bf(W1g[k * 512 + jj + wc * 32 + n]);
    }
    __syncthreads();
    if (wv == wc) {
#pragma unroll
      for (int i = 0; i < 2; ++i)
#pragma unroll
        for (int kt = 0; kt < 8; ++kt)
          w1f[i][kt] = *(const bf16x8*)&STG[(i * 16 + cl) * 264 + kt * 32 + q * 8];
    }
  }
  // ---- stage layer-2 weight frags (per-wave 64-col chunks) ----
  bf16x8 w2f[4][4];
  for (int wc = 0; wc < 4; ++wc) {
    __syncthreads();
    for (int idx = tid; idx < 64 * 128; idx += 256) {
      int n = idx & 63, k = idx >> 6;
      STG[n * 136 + k] = f2bf(W2g[(jj + k) * 256 + wc * 64 + n]);
    }
    __syncthreads();
    if (wv == wc) {
#pragma unroll
      for (int i = 0; i < 4; ++i)
#pragma unroll
        for (int kt = 0; kt < 4; ++kt)
          w2f[i][kt] = *(const bf16x8*)&STG[(i * 16 + cl) * 136 + kt * 32 + q * 8];
    }
  }

  if (tid < 128) B1[tid] = b1g[jj + tid];
  // zero x pad rows 4..15 (kept zero forever; updates touch rows 0..3 only)
  for (int idx = tid; idx < 12 * 264; idx += 256) Xs[4 * 264 + idx] = 0;

  // ---- per-thread state mapping: thread -> (row ub, cols us..us+3) ----
  const int ub = tid >> 6;
  const int us4 = tid & 63;
  const int us = us4 * 4;
  const int grow = 4 * c + ub;  // global batch row

  f32x4 xr = *(const f32x4*)(x0 + grow * 256 + us);  // fp32 master state
  f32x4 b2d = *(const f32x4*)(bd2 + us);
  f32x4 b2s = *(const f32x4*)(bs2 + us);

  {
    u16x4 xu;
#pragma unroll
    for (int i2 = 0; i2 < 4; ++i2) xu[i2] = f2bf(xr[i2]);
    *(u16x4*)&Xs[ub * 264 + us] = xu;
  }
  float* trow = out + (size_t)grow * (size_t)(NS + 1) * 256 + us;
  if (j == 0) *(f32x4*)trow = xr;  // trajectory slot 0 = x0

  __syncthreads();

  for (int t = 0; t < NS; ++t) {
    // prefetch this step's noise early (hidden behind GEMMs)
    f32x4 nf = *(const f32x4*)(fgn + ((size_t)t * 128 + grow) * 256 + us);

    // ---- GEMM1: h_pre[16,32(wave)] = x[16,256] @ W1slice ----
    f32x4 acc0 = {0.f, 0.f, 0.f, 0.f}, acc1 = {0.f, 0.f, 0.f, 0.f};
#pragma unroll
    for (int kt = 0; kt < 8; ++kt) {
      bf16x8 a = *(const bf16x8*)&Xs[cl * 264 + kt * 32 + q * 8];
      acc0 = MFMA16(a, w1f[0][kt], acc0);
      acc1 = MFMA16(a, w1f[1][kt], acc1);
    }
    // bias + tanh -> Hs (bf16), C-layout: row=q*4+r, col=tile*16+cl
#pragma unroll
    for (int i = 0; i < 2; ++i) {
      int col = (wv * 2 + i) * 16 + cl;
      float bb = B1[col];
      f32x4 v = i ? acc1 : acc0;
#pragma unroll
      for (int r = 0; r < 4; ++r)
        Hs[(q * 4 + r) * 136 + col] = f2bf(fast_tanh(v[r] + bb));
    }
    __syncthreads();

    // ---- GEMM2: partial[16,64(wave)] = h[16,128] @ W2slice ----
    f32x4 pacc[4] = {{0.f,0.f,0.f,0.f},{0.f,0.f,0.f,0.f},{0.f,0.f,0.f,0.f},{0.f,0.f,0.f,0.f}};
#pragma unroll
    for (int kt = 0; kt < 4; ++kt) {
      bf16x8 a = *(const bf16x8*)&Hs[cl * 136 + kt * 32 + q * 8];
#pragma unroll
      for (int i = 0; i < 4; ++i) pacc[i] = MFMA16(a, w2f[i][kt], pacc[i]);
    }

    // ---- publish partials as (value, tag=t+1) 8B pairs (rows live in q==0) ----
    float* pbase = part + ((size_t)((t & 1) * 32 + c) * 8 + j) * 2048;
    if (q == 0) {
#pragma unroll
      for (int i = 0; i < 4; ++i) {
        int col = (wv * 4 + i) * 16 + cl;
#pragma unroll
        for (int r = 0; r < 4; ++r) {
          u32x2 pr;
          pr[0] = __float_as_uint(pacc[i][r]);
          pr[1] = (unsigned)(t + 1);
          asm volatile("global_store_dwordx2 %0, %1, off sc0 sc1"
                       :: "v"(pbase + (size_t)(r * 256 + col) * 2), "v"(pr)
                       : "memory");
        }
      }
    }
    // NO drain here: gather loads are issued immediately so store latency and
    // load latency overlap; any load that beats a store is caught by its tag
    // and retried.

    // ---- gather all 8 partials; each 8B pair self-validates via its tag ----
    u32x4 g0, g1, g2, g3, g4, g5, g6, g7, g8, g9, g10, g11, g12, g13, g14, g15;
    {
      const uint64_t voff = (uint64_t)(ub * 2048 + us4 * 32);  // byte offset
      const float* gb = part + ((size_t)((t & 1) * 32 + c) * 8) * 2048;
      const uint64_t a0 = (uint64_t)gb + voff;
      const uint64_t a1 = a0 + 8192 * 1;
      const uint64_t a2 = a0 + 8192 * 2;
      const uint64_t a3 = a0 + 8192 * 3;
      const uint64_t a4 = a0 + 8192 * 4;
      const uint64_t a5 = a0 + 8192 * 5;
      const uint64_t a6 = a0 + 8192 * 6;
      const uint64_t a7 = a0 + 8192 * 7;
      const unsigned tg = (unsigned)(t + 1);
      int ok;
      do {
        asm volatile(
            "global_load_dwordx4 %0, %16, off sc0 sc1\n\t"
            "global_load_dwordx4 %1, %16, off offset:16 sc0 sc1\n\t"
            "global_load_dwordx4 %2, %17, off sc0 sc1\n\t"
            "global_load_dwordx4 %3, %17, off offset:16 sc0 sc1\n\t"
            "global_load_dwordx4 %4, %18, off sc0 sc1\n\t"
            "global_load_dwordx4 %5, %18, off offset:16 sc0 sc1\n\t"
            "global_load_dwordx4 %6, %19, off sc0 sc1\n\t"
            "global_load_dwordx4 %7, %19, off offset:16 sc0 sc1\n\t"
            "global_load_dwordx4 %8, %20, off sc0 sc1\n\t"
            "global_load_dwordx4 %9, %20, off offset:16 sc0 sc1\n\t"
            "global_load_dwordx4 %10, %21, off sc0 sc1\n\t"
            "global_load_dwordx4 %11, %21, off offset:16 sc0 sc1\n\t"
            "global_load_dwordx4 %12, %22, off sc0 sc1\n\t"
            "global_load_dwordx4 %13, %22, off offset:16 sc0 sc1\n\t"
            "global_load_dwordx4 %14, %23, off sc0 sc1\n\t"
            "global_load_dwordx4 %15, %23, off offset:16 sc0 sc1\n\t"
            "s_waitcnt vmcnt(0)"
            : "=&v"(g0), "=&v"(g1), "=&v"(g2), "=&v"(g3),
              "=&v"(g4), "=&v"(g5), "=&v"(g6), "=&v"(g7),
              "=&v"(g8), "=&v"(g9), "=&v"(g10), "=&v"(g11),
              "=&v"(g12), "=&v"(g13), "=&v"(g14), "=&v"(g15)
            : "v"(a0), "v"(a1), "v"(a2), "v"(a3),
              "v"(a4), "v"(a5), "v"(a6), "v"(a7)
            : "memory");
        ok = (g0[1] == tg) & (g0[3] == tg) & (g1[1] == tg) & (g1[3] == tg) &
             (g2[1] == tg) & (g2[3] == tg) & (g3[1] == tg) & (g3[3] == tg) &
             (g4[1] == tg) & (g4[3] == tg) & (g5[1] == tg) & (g5[3] == tg) &
             (g6[1] == tg) & (g6[3] == tg) & (g7[1] == tg) & (g7[3] == tg) &
             (g8[1] == tg) & (g8[3] == tg) & (g9[1] == tg) & (g9[3] == tg) &
             (g10[1] == tg) & (g10[3] == tg) & (g11[1] == tg) & (g11[3] == tg) &
             (g12[1] == tg) & (g12[3] == tg) & (g13[1] == tg) & (g13[3] == tg) &
             (g14[1] == tg) & (g14[3] == tg) & (g15[1] == tg) & (g15[3] == tg);
      } while (__builtin_expect(!ok, 0));
    }
    // pair layout per source: [v(us),tag, v(us+1),tag] [v(us+2),tag, v(us+3),tag]
    f32x4 dsum, ssum;
    dsum[0] = __uint_as_float(g0[0]) + __uint_as_float(g2[0]) +
              __uint_as_float(g4[0]) + __uint_as_float(g6[0]);
    dsum[1] = __uint_as_float(g0[2]) + __uint_as_float(g2[2]) +
              __uint_as_float(g4[2]) + __uint_as_float(g6[2]);
    dsum[2] = __uint_as_float(g1[0]) + __uint_as_float(g3[0]) +
              __uint_as_float(g5[0]) + __uint_as_float(g7[0]);
    dsum[3] = __uint_as_float(g1[2]) + __uint_as_float(g3[2]) +
              __uint_as_float(g5[2]) + __uint_as_float(g7[2]);
    ssum[0] = __uint_as_float(g8[0]) + __uint_as_float(g10[0]) +
              __uint_as_float(g12[0]) + __uint_as_float(g14[0]);
    ssum[1] = __uint_as_float(g8[2]) + __uint_as_float(g10[2]) +
              __uint_as_float(g12[2]) + __uint_as_float(g14[2]);
    ssum[2] = __uint_as_float(g9[0]) + __uint_as_float(g11[0]) +
              __uint_as_float(g13[0]) + __uint_as_float(g15[0]);
    ssum[3] = __uint_as_float(g9[2]) + __uint_as_float(g11[2]) +
              __uint_as_float(g13[2]) + __uint_as_float(g15[2]);

#pragma unroll
    for (int i2 = 0; i2 < 4; ++i2)
      xr[i2] += (dsum[i2] + b2d[i2]) * dt + (ssum[i2] + b2s[i2]) * (nf[i2] * nsc);

    {
      u16x4 xu;
#pragma unroll
      for (int i2 = 0; i2 < 4; ++i2) xu[i2] = f2bf(xr[i2]);
      *(u16x4*)&Xs[ub * 264 + us] = xu;
    }
    if (j == 0) *(f32x4*)(trow + (size_t)(t + 1) * 256) = xr;
    __syncthreads();
  }
}

extern "C" void kernel_launch(void* const* d_in, const int* in_sizes, int n_in,
                              void* d_out, int out_size, void* d_ws, size_t ws_size,
                              hipStream_t stream) {
  const float* x0  = (const float*)d_in[0];
  const float* Wd1 = (const float*)d_in[1];
  const float* bd1 = (const float*)d_in[2];
  const float* Wd2 = (const float*)d_in[3];
  const float* bd2 = (const float*)d_in[4];
  const float* Ws1 = (const float*)d_in[5];
  const float* bs1 = (const float*)d_in[6];
  const float* Ws2 = (const float*)d_in[7];
  const float* bs2 = (const float*)d_in[8];
  const float* rawh = (const float*)d_in[9];
  const float* fgn = (const float*)d_in[10];
  const int* nsp = (const int*)d_in[11];
  float* out = (float*)d_out;

  // 2 slots x 32 clusters x 8 wgs x 1024 (value,tag) pairs = 4 MB.
  // No memset needed: the 0xAA workspace poison never equals a valid tag
  // (tags are 1..1000), so poisoned pairs read as "not ready".
  float* part = (float*)d_ws;

  fsde_kernel<<<dim3(256), dim3(256), 0, stream>>>(
      x0, Wd1, bd1, Wd2, bd2, Ws1, bs1, Ws2, bs2, rawh, fgn, nsp, out, part);
}

// Round 6
// 3408.475 us; speedup vs baseline: 7.8293x; 1.2639x over previous
//
#include <hip/hip_runtime.h>
#include <hip/hip_bf16.h>
#include <stdint.h>

// NeuralFSDE: 1000 sequential steps of x += mlp_d(x)*dt + mlp_s(x)*(fgn*dt^H)
// B=128, S=256, Hd=512. Weight-stationary sharded design:
//   32 clusters x 8 wgs; cluster owns 4 batch rows; wg j holds a 128-wide
//   hidden slice of (drift|diff) MLP in registers; partials exchanged per step.
// Round 6: TAGGED-PAIR EXCHANGE + DRAIN.
//   R0 (flags): drain -> flag-store -> poll -> gather = ~3600cy exchange.
//   R5 (tags, no drain): gather raced peer stores -> ~1 retry/step -> 4208us.
//   This round: tags WITH a vmcnt(0) drain before the gather. All wgs drain
//   in parallel, so when our drain completes (~900cy) peer partials are
//   ~visible; the first gather attempt then succeeds -> exchange = 2 legs
//   (~1800cy), no flags, no polls, no barriers in the exchange.
//   Each partial is an 8B (fp32 value, u32 tag=t+1) pair stored by ONE
//   global_store_dwordx2 (naturally aligned -> single transaction, no tear);
//   the tag validates its own 8 bytes; mismatch -> bounded re-read.
//   No memset: workspace 0xAA poison never equals a valid tag (1..1000).
//   Liveness identical to R5 (ran to completion): tags are written uncondi-
//   tionally; double-buffer backpressure unchanged -> hang-impossible.
//   Arithmetic bit-identical to the 3035us baseline.

typedef __attribute__((ext_vector_type(8))) short bf16x8;
typedef __attribute__((ext_vector_type(4))) float f32x4;
typedef __attribute__((ext_vector_type(4))) unsigned short u16x4;
typedef __attribute__((ext_vector_type(2))) unsigned int u32x2;
typedef __attribute__((ext_vector_type(4))) unsigned int u32x4;

#define MFMA16(a, b, c) __builtin_amdgcn_mfma_f32_16x16x32_bf16((a), (b), (c), 0, 0, 0)

__device__ __forceinline__ unsigned short f2bf(float f) {
  union { float f; uint32_t u; } v; v.f = f;
  return (unsigned short)((v.u + 0x7fffu + ((v.u >> 16) & 1u)) >> 16);
}

__device__ __forceinline__ float fast_tanh(float z) {
  float az = __builtin_fabsf(z);
  float e = __expf(-2.0f * az);
  float r = (1.0f - e) * __builtin_amdgcn_rcpf(1.0f + e);
  return z < 0.0f ? -r : r;
}

__global__ __launch_bounds__(256, 1) void fsde_kernel(
    const float* __restrict__ x0,
    const float* __restrict__ Wd1, const float* __restrict__ bd1,
    const float* __restrict__ Wd2, const float* __restrict__ bd2,
    const float* __restrict__ Ws1, const float* __restrict__ bs1,
    const float* __restrict__ Ws2, const float* __restrict__ bs2,
    const float* __restrict__ rawh,
    const float* __restrict__ fgn,
    const int* __restrict__ nsp,
    float* __restrict__ out,
    float* __restrict__ part)   // [2][32][8][1024] (fp32,u32-tag) pairs = 4 MB
{
  // LDS: strides padded so stride % 32 dwords == 4 -> MFMA frag reads are
  // 2-way bank aliased (free, m136); rows 16B aligned for ds_read_b128.
  __shared__ __align__(16) unsigned short Xs[16 * 264];   // x tile, bf16
  __shared__ __align__(16) unsigned short Hs[16 * 136];   // hidden tile, bf16
  __shared__ __align__(16) unsigned short STG[8704];      // weight staging scratch
  __shared__ float B1[128];

  const int tid = threadIdx.x;
  const int lane = tid & 63;
  const int wv = tid >> 6;   // wave 0..3
  const int q = lane >> 4;   // quad 0..3
  const int cl = lane & 15;

  // block -> (cluster c, shard j); cluster's 8 blocks share bid%8 (same XCD
  // under round-robin dispatch -- perf heuristic only; correctness is
  // system-scope + tag-validated).
  const int bid = blockIdx.x;
  const int c = (bid & 7) * 4 + ((bid >> 3) >> 3);  // 0..31
  const int j = (bid >> 3) & 7;                     // 0..7

  const int NS = nsp[0];
  const float dt = 1.0f / (float)NS;  // T_MAX = 1.0
  const float Hh = 0.98f / (1.0f + expf(-rawh[0])) + 0.01f;
  const float nsc = expf(Hh * logf(dt));  // dt^H

  const float* W1g = (j < 4) ? Wd1 : Ws1;  // [256][512]
  const float* W2g = (j < 4) ? Wd2 : Ws2;  // [512][256]
  const float* b1g = (j < 4) ? bd1 : bs1;
  const int jj = (j & 3) * 128;  // hidden slice start

  // ---- stage layer-1 weight frags into registers (per-wave 32-col chunks) ----
  bf16x8 w1f[2][8];
  for (int wc = 0; wc < 4; ++wc) {
    __syncthreads();
    for (int idx = tid; idx < 32 * 256; idx += 256) {
      int n = idx & 31, k = idx >> 5;
      STG[n * 264 + k] = f2bf(W1g[k * 512 + jj + wc * 32 + n]);
    }
    __syncthreads();
    if (wv == wc) {
#pragma unroll
      for (int i = 0; i < 2; ++i)
#pragma unroll
        for (int kt = 0; kt < 8; ++kt)
          w1f[i][kt] = *(const bf16x8*)&STG[(i * 16 + cl) * 264 + kt * 32 + q * 8];
    }
  }
  // ---- stage layer-2 weight frags (per-wave 64-col chunks) ----
  bf16x8 w2f[4][4];
  for (int wc = 0; wc < 4; ++wc) {
    __syncthreads();
    for (int idx = tid; idx < 64 * 128; idx += 256) {
      int n = idx & 63, k = idx >> 6;
      STG[n * 136 + k] = f2bf(W2g[(jj + k) * 256 + wc * 64 + n]);
    }
    __syncthreads();
    if (wv == wc) {
#pragma unroll
      for (int i = 0; i < 4; ++i)
#pragma unroll
        for (int kt = 0; kt < 4; ++kt)
          w2f[i][kt] = *(const bf16x8*)&STG[(i * 16 + cl) * 136 + kt * 32 + q * 8];
    }
  }

  if (tid < 128) B1[tid] = b1g[jj + tid];
  // zero x pad rows 4..15 (kept zero forever; updates touch rows 0..3 only)
  for (int idx = tid; idx < 12 * 264; idx += 256) Xs[4 * 264 + idx] = 0;

  // ---- per-thread state mapping: thread -> (row ub, cols us..us+3) ----
  const int ub = tid >> 6;
  const int us4 = tid & 63;
  const int us = us4 * 4;
  const int grow = 4 * c + ub;  // global batch row

  f32x4 xr = *(const f32x4*)(x0 + grow * 256 + us);  // fp32 master state
  f32x4 b2d = *(const f32x4*)(bd2 + us);
  f32x4 b2s = *(const f32x4*)(bs2 + us);

  {
    u16x4 xu;
#pragma unroll
    for (int i2 = 0; i2 < 4; ++i2) xu[i2] = f2bf(xr[i2]);
    *(u16x4*)&Xs[ub * 264 + us] = xu;
  }
  float* trow = out + (size_t)grow * (size_t)(NS + 1) * 256 + us;
  if (j == 0) *(f32x4*)trow = xr;  // trajectory slot 0 = x0

  __syncthreads();

  for (int t = 0; t < NS; ++t) {
    // prefetch this step's noise early (hidden behind GEMMs)
    f32x4 nf = *(const f32x4*)(fgn + ((size_t)t * 128 + grow) * 256 + us);

    // ---- GEMM1: h_pre[16,32(wave)] = x[16,256] @ W1slice ----
    f32x4 acc0 = {0.f, 0.f, 0.f, 0.f}, acc1 = {0.f, 0.f, 0.f, 0.f};
#pragma unroll
    for (int kt = 0; kt < 8; ++kt) {
      bf16x8 a = *(const bf16x8*)&Xs[cl * 264 + kt * 32 + q * 8];
      acc0 = MFMA16(a, w1f[0][kt], acc0);
      acc1 = MFMA16(a, w1f[1][kt], acc1);
    }
    // bias + tanh -> Hs (bf16), C-layout: row=q*4+r, col=tile*16+cl
#pragma unroll
    for (int i = 0; i < 2; ++i) {
      int col = (wv * 2 + i) * 16 + cl;
      float bb = B1[col];
      f32x4 v = i ? acc1 : acc0;
#pragma unroll
      for (int r = 0; r < 4; ++r)
        Hs[(q * 4 + r) * 136 + col] = f2bf(fast_tanh(v[r] + bb));
    }
    __syncthreads();

    // ---- GEMM2: partial[16,64(wave)] = h[16,128] @ W2slice ----
    f32x4 pacc[4] = {{0.f,0.f,0.f,0.f},{0.f,0.f,0.f,0.f},{0.f,0.f,0.f,0.f},{0.f,0.f,0.f,0.f}};
#pragma unroll
    for (int kt = 0; kt < 4; ++kt) {
      bf16x8 a = *(const bf16x8*)&Hs[cl * 136 + kt * 32 + q * 8];
#pragma unroll
      for (int i = 0; i < 4; ++i) pacc[i] = MFMA16(a, w2f[i][kt], pacc[i]);
    }

    // ---- publish partials as (value, tag=t+1) 8B pairs (rows live in q==0) ----
    float* pbase = part + ((size_t)((t & 1) * 32 + c) * 8 + j) * 2048;
    if (q == 0) {
#pragma unroll
      for (int i = 0; i < 4; ++i) {
        int col = (wv * 4 + i) * 16 + cl;
#pragma unroll
        for (int r = 0; r < 4; ++r) {
          u32x2 pr;
          pr[0] = __float_as_uint(pacc[i][r]);
          pr[1] = (unsigned)(t + 1);
          asm volatile("global_store_dwordx2 %0, %1, off sc0 sc1"
                       :: "v"(pbase + (size_t)(r * 256 + col) * 2), "v"(pr)
                       : "memory");
        }
      }
    }
    // DRAIN own stores before gathering (the R5 lesson): all 256 wgs drain in
    // parallel, so by the time our drain completes (~900cy) every peer's
    // partials are ~visible and the first gather attempt succeeds. Without
    // this, the gather's memory-read beats peer visibility -> retry storm.
    asm volatile("s_waitcnt vmcnt(0)" ::: "memory");

    // ---- gather all 8 partials; each 8B pair self-validates via its tag ----
    u32x4 g0, g1, g2, g3, g4, g5, g6, g7, g8, g9, g10, g11, g12, g13, g14, g15;
    {
      const uint64_t voff = (uint64_t)(ub * 2048 + us4 * 32);  // byte offset
      const float* gb = part + ((size_t)((t & 1) * 32 + c) * 8) * 2048;
      const uint64_t a0 = (uint64_t)gb + voff;
      const uint64_t a1 = a0 + 8192 * 1;
      const uint64_t a2 = a0 + 8192 * 2;
      const uint64_t a3 = a0 + 8192 * 3;
      const uint64_t a4 = a0 + 8192 * 4;
      const uint64_t a5 = a0 + 8192 * 5;
      const uint64_t a6 = a0 + 8192 * 6;
      const uint64_t a7 = a0 + 8192 * 7;
      const unsigned tg = (unsigned)(t + 1);
      int ok;
      do {
        asm volatile(
            "global_load_dwordx4 %0, %16, off sc0 sc1\n\t"
            "global_load_dwordx4 %1, %16, off offset:16 sc0 sc1\n\t"
            "global_load_dwordx4 %2, %17, off sc0 sc1\n\t"
            "global_load_dwordx4 %3, %17, off offset:16 sc0 sc1\n\t"
            "global_load_dwordx4 %4, %18, off sc0 sc1\n\t"
            "global_load_dwordx4 %5, %18, off offset:16 sc0 sc1\n\t"
            "global_load_dwordx4 %6, %19, off sc0 sc1\n\t"
            "global_load_dwordx4 %7, %19, off offset:16 sc0 sc1\n\t"
            "global_load_dwordx4 %8, %20, off sc0 sc1\n\t"
            "global_load_dwordx4 %9, %20, off offset:16 sc0 sc1\n\t"
            "global_load_dwordx4 %10, %21, off sc0 sc1\n\t"
            "global_load_dwordx4 %11, %21, off offset:16 sc0 sc1\n\t"
            "global_load_dwordx4 %12, %22, off sc0 sc1\n\t"
            "global_load_dwordx4 %13, %22, off offset:16 sc0 sc1\n\t"
            "global_load_dwordx4 %14, %23, off sc0 sc1\n\t"
            "global_load_dwordx4 %15, %23, off offset:16 sc0 sc1\n\t"
            "s_waitcnt vmcnt(0)"
            : "=&v"(g0), "=&v"(g1), "=&v"(g2), "=&v"(g3),
              "=&v"(g4), "=&v"(g5), "=&v"(g6), "=&v"(g7),
              "=&v"(g8), "=&v"(g9), "=&v"(g10), "=&v"(g11),
              "=&v"(g12), "=&v"(g13), "=&v"(g14), "=&v"(g15)
            : "v"(a0), "v"(a1), "v"(a2), "v"(a3),
              "v"(a4), "v"(a5), "v"(a6), "v"(a7)
            : "memory");
        ok = (g0[1] == tg) & (g0[3] == tg) & (g1[1] == tg) & (g1[3] == tg) &
             (g2[1] == tg) & (g2[3] == tg) & (g3[1] == tg) & (g3[3] == tg) &
             (g4[1] == tg) & (g4[3] == tg) & (g5[1] == tg) & (g5[3] == tg) &
             (g6[1] == tg) & (g6[3] == tg) & (g7[1] == tg) & (g7[3] == tg) &
             (g8[1] == tg) & (g8[3] == tg) & (g9[1] == tg) & (g9[3] == tg) &
             (g10[1] == tg) & (g10[3] == tg) & (g11[1] == tg) & (g11[3] == tg) &
             (g12[1] == tg) & (g12[3] == tg) & (g13[1] == tg) & (g13[3] == tg) &
             (g14[1] == tg) & (g14[3] == tg) & (g15[1] == tg) & (g15[3] == tg);
      } while (__builtin_expect(!ok, 0));
    }
    // pair layout per source: [v(us),tag, v(us+1),tag] [v(us+2),tag, v(us+3),tag]
    f32x4 dsum, ssum;
    dsum[0] = __uint_as_float(g0[0]) + __uint_as_float(g2[0]) +
              __uint_as_float(g4[0]) + __uint_as_float(g6[0]);
    dsum[1] = __uint_as_float(g0[2]) + __uint_as_float(g2[2]) +
              __uint_as_float(g4[2]) + __uint_as_float(g6[2]);
    dsum[2] = __uint_as_float(g1[0]) + __uint_as_float(g3[0]) +
              __uint_as_float(g5[0]) + __uint_as_float(g7[0]);
    dsum[3] = __uint_as_float(g1[2]) + __uint_as_float(g3[2]) +
              __uint_as_float(g5[2]) + __uint_as_float(g7[2]);
    ssum[0] = __uint_as_float(g8[0]) + __uint_as_float(g10[0]) +
              __uint_as_float(g12[0]) + __uint_as_float(g14[0]);
    ssum[1] = __uint_as_float(g8[2]) + __uint_as_float(g10[2]) +
              __uint_as_float(g12[2]) + __uint_as_float(g14[2]);
    ssum[2] = __uint_as_float(g9[0]) + __uint_as_float(g11[0]) +
              __uint_as_float(g13[0]) + __uint_as_float(g15[0]);
    ssum[3] = __uint_as_float(g9[2]) + __uint_as_float(g11[2]) +
              __uint_as_float(g13[2]) + __uint_as_float(g15[2]);

#pragma unroll
    for (int i2 = 0; i2 < 4; ++i2)
      xr[i2] += (dsum[i2] + b2d[i2]) * dt + (ssum[i2] + b2s[i2]) * (nf[i2] * nsc);

    {
      u16x4 xu;
#pragma unroll
      for (int i2 = 0; i2 < 4; ++i2) xu[i2] = f2bf(xr[i2]);
      *(u16x4*)&Xs[ub * 264 + us] = xu;
    }
    if (j == 0) *(f32x4*)(trow + (size_t)(t + 1) * 256) = xr;
    __syncthreads();
  }
}

extern "C" void kernel_launch(void* const* d_in, const int* in_sizes, int n_in,
                              void* d_out, int out_size, void* d_ws, size_t ws_size,
                              hipStream_t stream) {
  const float* x0  = (const float*)d_in[0];
  const float* Wd1 = (const float*)d_in[1];
  const float* bd1 = (const float*)d_in[2];
  const float* Wd2 = (const float*)d_in[3];
  const float* bd2 = (const float*)d_in[4];
  const float* Ws1 = (const float*)d_in[5];
  const float* bs1 = (const float*)d_in[6];
  const float* Ws2 = (const float*)d_in[7];
  const float* bs2 = (const float*)d_in[8];
  const float* rawh = (const float*)d_in[9];
  const float* fgn = (const float*)d_in[10];
  const int* nsp = (const int*)d_in[11];
  float* out = (float*)d_out;

  // 2 slots x 32 clusters x 8 wgs x 1024 (value,tag) pairs = 4 MB.
  // No memset needed: the 0xAA workspace poison never equals a valid tag
  // (tags are 1..1000), so poisoned pairs read as "not ready".
  float* part = (float*)d_ws;

  fsde_kernel<<<dim3(256), dim3(256), 0, stream>>>(
      x0, Wd1, bd1, Wd2, bd2, Ws1, bs1, Ws2, bs2, rawh, fgn, nsp, out, part);
}